// Round 4
// baseline (1486.746 us; speedup 1.0000x reference)
//
#include <hip/hip_runtime.h>
#include <hip/hip_bf16.h>

#define NN 50000
#define NE 1600000
#define HD 128
#define NR 16
#define NCB 1563                 // coarse bins, 32 dsts each
#define S2B 512                  // sort blocks
#define EPB (NE / S2B)           // 3125 edges per sort block (exact)
#define SLOT 2048                // rec slots per bin
#define PREPH_BLKS 6250
#define PREPW_BLKS 1024

typedef __bf16 bf16x8 __attribute__((ext_vector_type(8)));
typedef unsigned short u16x8 __attribute__((ext_vector_type(8)));
typedef unsigned int u32x4 __attribute__((ext_vector_type(4)));
typedef float f32x4 __attribute__((ext_vector_type(4)));

__device__ __forceinline__ unsigned short f2bf(float f) {
    union { float f; unsigned int u; } v; v.f = f;
    unsigned int u = v.u;
    u += 0x7FFFu + ((u >> 16) & 1u);   // round-to-nearest-even
    return (unsigned short)(u >> 16);
}
__device__ __forceinline__ float bflo(unsigned int u) {
    union { unsigned int u; float f; } v; v.u = u << 16; return v.f;
}
__device__ __forceinline__ float bfhi(unsigned int u) {
    union { unsigned int u; float f; } v; v.u = u & 0xFFFF0000u; return v.f;
}

// ---------------- 1: prep_h + prep_w + coarse histogram -------------------
__global__ __launch_bounds__(256) void prep_all(const int* __restrict__ node_ids,
                                                const float* __restrict__ emb,
                                                unsigned short* __restrict__ h_bf,
                                                const float* __restrict__ W,
                                                unsigned short* __restrict__ Wt,
                                                const int* __restrict__ dst,
                                                int* __restrict__ cntM) {
    const int b = blockIdx.x;
    const int t = threadIdx.x;
    if (b < PREPH_BLKS) {
        int gid = b * 256 + t;
        int row = gid >> 5;
        int c = (gid & 31) << 2;
        int nid = node_ids[row];
        if (nid < 0) nid = 0; if (nid >= NN) nid = NN - 1;
        float4 v = *(const float4*)(emb + (size_t)nid * HD + c);
        ushort4 o;
        o.x = f2bf(v.x); o.y = f2bf(v.y); o.z = f2bf(v.z); o.w = f2bf(v.w);
        *(ushort4*)(h_bf + (size_t)row * HD + c) = o;
    } else if (b < PREPH_BLKS + PREPW_BLKS) {
        int gid = (b - PREPH_BLKS) * 256 + t;
        int r = gid >> 14;
        int idx = gid & 16383;
        int k = idx >> 7;
        int o = idx & 127;
        Wt[(size_t)r * 16384 + (size_t)o * 128 + k] = f2bf(W[gid]);
    } else {
        // coarse histogram (LDS only), block-major count matrix
        __shared__ int h[NCB];
        const int sb = b - PREPH_BLKS - PREPW_BLKS;    // 0..511
        for (int i = t; i < NCB; i += 256) h[i] = 0;
        __syncthreads();
        const int base = sb * EPB;
        for (int i = t; i < EPB; i += 256)
            atomicAdd(&h[((unsigned)dst[base + i]) >> 5], 1);
        __syncthreads();
        for (int i = t; i < NCB; i += 256) cntM[sb * NCB + i] = h[i];
    }
}

// ---------------- 2: per-bin scan of 512 block-counts ---------------------
__global__ __launch_bounds__(256) void scanBins(int* __restrict__ cntM,
                                                int* __restrict__ binN) {
    __shared__ int s[256];
    const int t = threadIdx.x;
    const int bin = blockIdx.x;
    int v0 = cntM[(2 * t) * NCB + bin];
    int v1 = cntM[(2 * t + 1) * NCB + bin];
    s[t] = v0 + v1;
    __syncthreads();
    for (int off = 1; off < 256; off <<= 1) {
        int x = (t >= off) ? s[t - off] : 0;
        __syncthreads();
        s[t] += x;
        __syncthreads();
    }
    int total = s[255];
    int e0 = s[t] - v0 - v1;
    int e1 = e0 + v0;
    cntM[(2 * t) * NCB + bin]     = bin * SLOT + (e0 < SLOT ? e0 : SLOT);
    cntM[(2 * t + 1) * NCB + bin] = bin * SLOT + (e1 < SLOT ? e1 : SLOT);
    if (t == 255) binN[bin] = (total < SLOT) ? total : SLOT;
}

// ---------------- 3: coarse scatter (standalone, LDS cursors) -------------
__global__ __launch_bounds__(256) void s2_scatter(const int* __restrict__ src,
                                                  const int* __restrict__ dst,
                                                  const int* __restrict__ rel,
                                                  const float* __restrict__ norm,
                                                  const int* __restrict__ cntM,
                                                  uint2* __restrict__ recs) {
    __shared__ int cur[NCB];
    const int t = threadIdx.x, sb = blockIdx.x;
    for (int i = t; i < NCB; i += 256) cur[i] = cntM[sb * NCB + i];
    __syncthreads();
    const int base = sb * EPB;
    for (int i = t; i < EPB; i += 256) {
        int e = base + i;
        int d = dst[e];
        int bin = ((unsigned)d) >> 5;
        int p = atomicAdd(&cur[bin], 1);
        int binEnd = (bin + 1) * SLOT;
        if (p < binEnd) {
            unsigned x = (unsigned)src[e] | ((unsigned)rel[e] << 16)
                       | ((unsigned)(d & 31) << 20);
            recs[p] = make_uint2(x, __float_as_uint(norm[e]));
        }
    }
}

// ---------------- 4: fused rel-sort + LDS-atomic aggregate + MFMA ---------
// out[d] = sum_r W[r]^T m[d,r],  m[d,r] = sum_{e:dst=d,rel=r} norm_e h[src_e]
// Per rel: waves walk contiguous rel-segment slices 8-deep BRANCHLESS
// (clamped tail lanes re-read the segment head: L1-hot, norm=0), and
// ds_add_f32 into mF[32][128] keyed by sub-dst.  mF is de-interleaved
// (even cols 0..63 / odd 64..127: write adds 2-way bank-free) and
// XOR-swizzled (word ^= (sub&7)<<2: frag b128 reads ~2-way = free).
__global__ __launch_bounds__(256, 4) void seg_mm(const int* __restrict__ binN,
                                                 const uint2* __restrict__ recs,
                                                 const unsigned int* __restrict__ hb,
                                                 const unsigned short* __restrict__ Wt,
                                                 float* __restrict__ out) {
    __shared__ unsigned pkS[SLOT];           // 8 KB: src | sub<<16, rel-sorted
    __shared__ float    normS[SLOT];         // 8 KB
    __shared__ float    mF[32 * 128];        // 16 KB f32 m-tile
    __shared__ int h16[16], sbx[17], cur[16];
    const int t = threadIdx.x;
    const int bin = blockIdx.x;
    const int n = binN[bin];
    const uint2* rg = recs + (size_t)bin * SLOT;

    if (t < 16) h16[t] = 0;
    __syncthreads();
    for (int i = t; i < n; i += 256)
        atomicAdd(&h16[(rg[i].x >> 16) & 15], 1);
    __syncthreads();
    if (t == 0) {
        int run = 0;
        #pragma unroll
        for (int s = 0; s < 16; ++s) { sbx[s] = run; run += h16[s]; }
        sbx[16] = run;
    }
    __syncthreads();
    if (t < 16) cur[t] = sbx[t];
    for (int i = t; i < 32 * 128; i += 256) mF[i] = 0.f;   // zero for r=0
    __syncthreads();
    for (int i = t; i < n; i += 256) {
        uint2 r = rg[i];
        int p = atomicAdd(&cur[(r.x >> 16) & 15], 1);
        pkS[p] = (r.x & 0xFFFFu) | (((r.x >> 20) & 31u) << 16);
        normS[p] = __uint_as_float(r.y);
    }
    __syncthreads();

    const int lane = t & 63;
    const int w = t >> 6;
    const int l15 = lane & 15, lhi = lane >> 4;
    const int colBase = w * 32;              // wave's 32 output cols

    f32x4 acc[2][2];
    #pragma unroll
    for (int i = 0; i < 2; ++i)
        #pragma unroll
        for (int j = 0; j < 2; ++j)
            acc[i][j] = (f32x4){0.f, 0.f, 0.f, 0.f};

    for (int r = 0; r < NR; ++r) {
        const int s = sbx[r], e = sbx[r + 1];
        // ---- branchless 8-deep gather + LDS-atomic accumulate ----
        for (int i0 = s + w * 8; i0 < e; i0 += 32) {
            unsigned u8[8]; float nm[8]; int sb8[8];
            #pragma unroll
            for (int k = 0; k < 8; ++k) {
                int idx = i0 + k;
                int ci = idx < e ? idx : s;          // clamp: dup row, L1-hot
                unsigned pk = pkS[ci];
                nm[k] = idx < e ? normS[ci] : 0.f;
                sb8[k] = (int)(pk >> 16);
                u8[k] = hb[(size_t)(pk & 0xFFFFu) * 64u + (unsigned)lane];
            }
            #pragma unroll
            for (int k = 0; k < 8; ++k) {
                int sw = lane ^ ((sb8[k] & 7) << 2);
                atomicAdd(&mF[sb8[k] * 128 + sw], bflo(u8[k]) * nm[k]);
                atomicAdd(&mF[sb8[k] * 128 + (sw | 64)], bfhi(u8[k]) * nm[k]);
            }
        }
        __syncthreads();                     // bar1: mF complete

        // ---- MFMA: acc += m[32x128] @ W_r[128x128] (wave's 32 cols) ----
        const unsigned short* wp = Wt + ((size_t)r << 14);
        #pragma unroll
        for (int kt = 0; kt < 4; ++kt) {
            const int bo = kt * 16 + lhi * 4;        // even-word base
            const int ko = kt * 32 + lhi * 8;        // col base
            bf16x8 aF[2], bF[2];
            #pragma unroll
            for (int ms = 0; ms < 2; ++ms) {
                int row = ms * 16 + l15;
                int sw = bo ^ ((row & 7) << 2);
                const float* mp = &mF[row * 128];
                f32x4 ev = *(const f32x4*)(mp + sw);
                f32x4 od = *(const f32x4*)(mp + (sw | 64));
                u32x4 raw;
                #pragma unroll
                for (int j = 0; j < 4; ++j) {
                    union { __hip_bfloat162 h2; unsigned u; } cv;
                    cv.h2 = __float22bfloat162_rn(make_float2(ev[j], od[j]));
                    raw[j] = cv.u;           // lo = even col, hi = odd col
                }
                aF[ms] = __builtin_bit_cast(bf16x8, raw);
            }
            #pragma unroll
            for (int nt = 0; nt < 2; ++nt) {
                u16x8 rawB = *(const u16x8*)(wp + (size_t)(colBase + nt * 16 + l15) * 128 + ko);
                bF[nt] = __builtin_bit_cast(bf16x8, rawB);
            }
            #pragma unroll
            for (int ms = 0; ms < 2; ++ms)
                #pragma unroll
                for (int nt = 0; nt < 2; ++nt)
                    acc[ms][nt] = __builtin_amdgcn_mfma_f32_16x16x32_bf16(
                        aF[ms], bF[nt], acc[ms][nt], 0, 0, 0);
        }
        __syncthreads();                     // bar2: all frag reads done
        if (r < NR - 1) {
            for (int i = t; i < 32 * 128; i += 256) mF[i] = 0.f;
        }
        __syncthreads();                     // bar3: zero done before next agg
    }

    // ---- epilogue: C frag row = lhi*4+reg, col = l15 ----
    const int dbase = bin * 32;
    #pragma unroll
    for (int ms = 0; ms < 2; ++ms) {
        #pragma unroll
        for (int reg = 0; reg < 4; ++reg) {
            int d = dbase + ms * 16 + lhi * 4 + reg;
            if (d < NN) {
                #pragma unroll
                for (int nt = 0; nt < 2; ++nt)
                    out[(size_t)d * 128 + colBase + nt * 16 + l15] = acc[ms][nt][reg];
            }
        }
    }
}

// ---------------- launch ---------------------------------------------------

extern "C" void kernel_launch(void* const* d_in, const int* in_sizes, int n_in,
                              void* d_out, int out_size, void* d_ws, size_t ws_size,
                              hipStream_t stream) {
    const int* node_ids = (const int*)d_in[0];
    const int* src      = (const int*)d_in[1];
    const int* dst      = (const int*)d_in[2];
    const int* rel      = (const int*)d_in[3];
    const float* norm   = (const float*)d_in[4];
    const float* emb    = (const float*)d_in[5];
    const float* W      = (const float*)d_in[6];
    float* out = (float*)d_out;

    char* ws = (char*)d_ws;
    unsigned short* h_bf = (unsigned short*)(ws);              // 12,800,000 B
    unsigned short* Wt   = (unsigned short*)(ws + 12800000);   //    524,288 B
    int* cntM            = (int*)(ws + 13324288);              //  3,201,024 B
    int* binN            = (int*)(ws + 16525312);              //      6,252 B
    uint2* recs          = (uint2*)(ws + 16531712);            // 25,608,192 B
    // total ~42.1 MB

    prep_all<<<PREPH_BLKS + PREPW_BLKS + S2B, 256, 0, stream>>>(
        node_ids, emb, h_bf, W, Wt, dst, cntM);
    scanBins<<<NCB, 256, 0, stream>>>(cntM, binN);
    s2_scatter<<<S2B, 256, 0, stream>>>(src, dst, rel, norm, cntM, recs);
    seg_mm<<<NCB, 256, 0, stream>>>(binN, recs,
                                    (const unsigned int*)h_bf, Wt, out);
}

// Round 5
// 522.201 us; speedup vs baseline: 2.8471x; 2.8471x over previous
//
#include <hip/hip_runtime.h>
#include <hip/hip_bf16.h>

#define NN 50000
#define NE 1600000
#define HD 128
#define NR 16
#define NCB 1563                 // coarse bins, 32 dsts each
#define SLOT 2048                // rec slots per bin
#define PREPH_BLKS 6250
#define PREPW_BLKS 1024
#define SCAT_BLKS 6250

typedef __bf16 bf16x8 __attribute__((ext_vector_type(8)));
typedef unsigned short u16x8 __attribute__((ext_vector_type(8)));
typedef unsigned int u32x4 __attribute__((ext_vector_type(4)));
typedef float f32x4 __attribute__((ext_vector_type(4)));

__device__ __forceinline__ unsigned short f2bf(float f) {
    union { float f; unsigned int u; } v; v.f = f;
    unsigned int u = v.u;
    u += 0x7FFFu + ((u >> 16) & 1u);   // round-to-nearest-even
    return (unsigned short)(u >> 16);
}
__device__ __forceinline__ float bflo(unsigned int u) {
    union { unsigned int u; float f; } v; v.u = u << 16; return v.f;
}
__device__ __forceinline__ float bfhi(unsigned int u) {
    union { unsigned int u; float f; } v; v.u = u & 0xFFFF0000u; return v.f;
}

// ---------------- 1: prep_h + prep_w + zero bin cursors -------------------
__global__ __launch_bounds__(256) void prep_all(const int* __restrict__ node_ids,
                                                const float* __restrict__ emb,
                                                unsigned short* __restrict__ h_bf,
                                                const float* __restrict__ W,
                                                unsigned short* __restrict__ Wt,
                                                int* __restrict__ gcur) {
    const int b = blockIdx.x;
    const int t = threadIdx.x;
    if (b < PREPH_BLKS) {
        int gid = b * 256 + t;
        int row = gid >> 5;
        int c = (gid & 31) << 2;
        int nid = node_ids[row];
        if (nid < 0) nid = 0; if (nid >= NN) nid = NN - 1;
        float4 v = *(const float4*)(emb + (size_t)nid * HD + c);
        ushort4 o;
        o.x = f2bf(v.x); o.y = f2bf(v.y); o.z = f2bf(v.z); o.w = f2bf(v.w);
        *(ushort4*)(h_bf + (size_t)row * HD + c) = o;
    } else if (b < PREPH_BLKS + PREPW_BLKS) {
        int gid = (b - PREPH_BLKS) * 256 + t;
        int r = gid >> 14;
        int idx = gid & 16383;
        int k = idx >> 7;
        int o = idx & 127;
        Wt[(size_t)r * 16384 + (size_t)o * 128 + k] = f2bf(W[gid]);
    } else {
        for (int i = t; i < NCB; i += 256) gcur[i] = 0;
    }
}

// ---------------- 2: direct global-atomic scatter -------------------------
__global__ __launch_bounds__(256) void scat(const int* __restrict__ src,
                                            const int* __restrict__ dst,
                                            const int* __restrict__ rel,
                                            const float* __restrict__ norm,
                                            int* __restrict__ gcur,
                                            uint2* __restrict__ recs) {
    int e = blockIdx.x * 256 + threadIdx.x;
    if (e >= NE) return;
    int d = dst[e];
    int bin = ((unsigned)d) >> 5;
    int p = atomicAdd(&gcur[bin], 1);
    if (p < SLOT) {
        unsigned x = (unsigned)src[e] | ((unsigned)rel[e] << 16)
                   | ((unsigned)(d & 31) << 20);
        recs[(size_t)bin * SLOT + p] = make_uint2(x, __float_as_uint(norm[e]));
    }
}

// ---------------- 3: fused 64-bucket sort + RMW aggregate + MFMA ----------
// out[d] = sum_r W[r]^T m[d,r],  m[d,r] = sum_{e:dst=d,rel=r} norm_e h[src_e]
// Bucket key = rel*4 + (sub&3): wave w owns bucket r*4+w, hence exclusively
// owns mF rows with sub%4==w -> plain ds_read/ds_write RMW, NO atomics
// (DS pipe is in-order per wave; rows disjoint across waves).
// Whole wave processes one edge per step (lane = cols 2*lane, 2*lane+1),
// 8 gathers in flight from L2/L3-resident h_bf.
// mF[32][128] f32, XOR-swizzle word ^= (row&7)<<3: RMW conflict-free,
// A-frag b128 reads 4-way (~1.58x, acceptable).
__global__ __launch_bounds__(256, 4) void seg_mm(const int* __restrict__ gcur,
                                                 const uint2* __restrict__ recs,
                                                 const unsigned int* __restrict__ hb,
                                                 const unsigned short* __restrict__ Wt,
                                                 float* __restrict__ out) {
    __shared__ unsigned pkS[SLOT];               // 8 KB: src | sub<<16, sorted
    __shared__ float    normS[SLOT];             // 8 KB
    __shared__ __align__(16) float mF[32 * 128]; // 16 KB (raw staging first)
    __shared__ int h64[64], sbx[65], cur[64];
    const int t = threadIdx.x;
    const int bin = blockIdx.x;
    int n = gcur[bin]; if (n > SLOT) n = SLOT;
    const uint2* rg = recs + (size_t)bin * SLOT;
    uint2* raw = (uint2*)mF;                     // SLOT*8B == 16KB == mF

    if (t < 64) h64[t] = 0;
    __syncthreads();
    for (int i = t; i < n; i += 256) {
        uint2 rc = rg[i];
        raw[i] = rc;
        atomicAdd(&h64[((rc.x >> 16) & 15) * 4 + ((rc.x >> 20) & 3)], 1);
    }
    __syncthreads();
    if (t == 0) {
        int run = 0;
        #pragma unroll
        for (int s = 0; s < 64; ++s) { sbx[s] = run; run += h64[s]; }
        sbx[64] = run;
    }
    __syncthreads();
    if (t < 64) cur[t] = sbx[t];
    __syncthreads();
    for (int i = t; i < n; i += 256) {
        uint2 rc = raw[i];
        int key = ((rc.x >> 16) & 15) * 4 + ((rc.x >> 20) & 3);
        int p = atomicAdd(&cur[key], 1);         // int atomic: native ds op
        pkS[p] = (rc.x & 0xFFFFu) | (((rc.x >> 20) & 31u) << 16);
        normS[p] = __uint_as_float(rc.y);
    }
    __syncthreads();
    for (int i = t; i < 32 * 128; i += 256) mF[i] = 0.f;   // raw dead now
    __syncthreads();

    const int lane = t & 63;
    const int w = t >> 6;
    const int l15 = lane & 15, lhi = lane >> 4;
    const int colBase = w * 32;                  // wave's 32 output cols
    const int lane2 = 2 * lane;

    f32x4 acc[2][2];
    #pragma unroll
    for (int i = 0; i < 2; ++i)
        #pragma unroll
        for (int j = 0; j < 2; ++j)
            acc[i][j] = (f32x4){0.f, 0.f, 0.f, 0.f};

    for (int r = 0; r < NR; ++r) {
        const int s = sbx[r * 4 + w], e = sbx[r * 4 + w + 1];
        // ---- branchless 8-deep gather + exclusive-row RMW accumulate ----
        for (int i0 = s; i0 < e; i0 += 8) {
            unsigned u8[8]; float nm[8]; int sb8[8];
            #pragma unroll
            for (int k = 0; k < 8; ++k) {
                int idx = i0 + k;
                int ci = idx < e ? idx : s;      // clamp: owned row, nm=0
                unsigned pk = pkS[ci];
                nm[k] = idx < e ? normS[ci] : 0.f;
                sb8[k] = (int)((pk >> 16) & 31u);
                u8[k] = hb[(size_t)(pk & 0xFFFFu) * 64u + (unsigned)lane];
            }
            #pragma unroll
            for (int k = 0; k < 8; ++k) {
                int woff = (sb8[k] << 7) + (lane2 ^ ((sb8[k] & 7) << 3));
                float2* mp = (float2*)&mF[woff];
                float2 v = *mp;                  // in-order DS pipe: RAW safe
                v.x += bflo(u8[k]) * nm[k];
                v.y += bfhi(u8[k]) * nm[k];
                *mp = v;
            }
        }
        __syncthreads();                         // bar1: mF complete

        // ---- MFMA: acc += m[32x128] @ W_r[128x128] (wave's 32 cols) ----
        const unsigned short* wp = Wt + ((size_t)r << 14);
        #pragma unroll
        for (int kt = 0; kt < 4; ++kt) {
            const int c0 = kt * 32 + lhi * 8;    // col/word base (mult of 8)
            bf16x8 aF[2], bF[2];
            #pragma unroll
            for (int ms = 0; ms < 2; ++ms) {
                int row = ms * 16 + l15;
                const float* mp = &mF[(row << 7) + (c0 ^ ((row & 7) << 3))];
                f32x4 f0 = *(const f32x4*)mp;
                f32x4 f1 = *(const f32x4*)(mp + 4);
                u32x4 rv;
                #pragma unroll
                for (int j = 0; j < 2; ++j) {
                    union { __hip_bfloat162 h2; unsigned u; } cv;
                    cv.h2 = __float22bfloat162_rn(make_float2(f0[2 * j], f0[2 * j + 1]));
                    rv[j] = cv.u;
                }
                #pragma unroll
                for (int j = 0; j < 2; ++j) {
                    union { __hip_bfloat162 h2; unsigned u; } cv;
                    cv.h2 = __float22bfloat162_rn(make_float2(f1[2 * j], f1[2 * j + 1]));
                    rv[2 + j] = cv.u;
                }
                aF[ms] = __builtin_bit_cast(bf16x8, rv);
            }
            #pragma unroll
            for (int nt = 0; nt < 2; ++nt) {
                u16x8 rawB = *(const u16x8*)(wp + (size_t)(colBase + nt * 16 + l15) * 128 + c0);
                bF[nt] = __builtin_bit_cast(bf16x8, rawB);
            }
            #pragma unroll
            for (int ms = 0; ms < 2; ++ms)
                #pragma unroll
                for (int nt = 0; nt < 2; ++nt)
                    acc[ms][nt] = __builtin_amdgcn_mfma_f32_16x16x32_bf16(
                        aF[ms], bF[nt], acc[ms][nt], 0, 0, 0);
        }
        __syncthreads();                         // bar2: frag reads done
        if (r < NR - 1) {
            for (int i = t; i < 32 * 128; i += 256) mF[i] = 0.f;
        }
        __syncthreads();                         // bar3: zero done
    }

    // ---- epilogue: C frag row = lhi*4+reg, col = l15 ----
    const int dbase = bin * 32;
    #pragma unroll
    for (int ms = 0; ms < 2; ++ms) {
        #pragma unroll
        for (int reg = 0; reg < 4; ++reg) {
            int d = dbase + ms * 16 + lhi * 4 + reg;
            if (d < NN) {
                #pragma unroll
                for (int nt = 0; nt < 2; ++nt)
                    out[(size_t)d * 128 + colBase + nt * 16 + l15] = acc[ms][nt][reg];
            }
        }
    }
}

// ---------------- launch ---------------------------------------------------

extern "C" void kernel_launch(void* const* d_in, const int* in_sizes, int n_in,
                              void* d_out, int out_size, void* d_ws, size_t ws_size,
                              hipStream_t stream) {
    const int* node_ids = (const int*)d_in[0];
    const int* src      = (const int*)d_in[1];
    const int* dst      = (const int*)d_in[2];
    const int* rel      = (const int*)d_in[3];
    const float* norm   = (const float*)d_in[4];
    const float* emb    = (const float*)d_in[5];
    const float* W      = (const float*)d_in[6];
    float* out = (float*)d_out;

    char* ws = (char*)d_ws;
    unsigned short* h_bf = (unsigned short*)(ws);              // 12,800,000 B
    unsigned short* Wt   = (unsigned short*)(ws + 12800000);   //    524,288 B
    int* gcur            = (int*)(ws + 13324288);              //      8,192 B (NCB used)
    uint2* recs          = (uint2*)(ws + 13332480);            // 25,608,192 B
    // total ~38.9 MB

    prep_all<<<PREPH_BLKS + PREPW_BLKS + 1, 256, 0, stream>>>(
        node_ids, emb, h_bf, W, Wt, gcur);
    scat<<<SCAT_BLKS, 256, 0, stream>>>(src, dst, rel, norm, gcur, recs);
    seg_mm<<<NCB, 256, 0, stream>>>(gcur, recs,
                                    (const unsigned int*)h_bf, Wt, out);
}

// Round 6
// 408.494 us; speedup vs baseline: 3.6396x; 1.2784x over previous
//
#include <hip/hip_runtime.h>
#include <hip/hip_bf16.h>

#define NN 50000
#define NE 1600000
#define HD 128
#define NR 16
#define NCB 1563                 // coarse bins, 32 dsts each
#define NSL 16                   // scatter slices (contention privatization)
#define SCAP 128                 // per-slice record cap (exp 64, 8-sigma ok)
#define SLOT 2048                // NSL*SCAP rec slots per bin
#define PREPH_BLKS 6250
#define PREPW_BLKS 1024
#define SCAT_BLKS 6250

typedef __bf16 bf16x8 __attribute__((ext_vector_type(8)));
typedef unsigned short u16x8 __attribute__((ext_vector_type(8)));
typedef unsigned int u32x4 __attribute__((ext_vector_type(4)));
typedef float f32x4 __attribute__((ext_vector_type(4)));

__device__ __forceinline__ unsigned short f2bf(float f) {
    union { float f; unsigned int u; } v; v.f = f;
    unsigned int u = v.u;
    u += 0x7FFFu + ((u >> 16) & 1u);   // round-to-nearest-even
    return (unsigned short)(u >> 16);
}
__device__ __forceinline__ float bflo(unsigned int u) {
    union { unsigned int u; float f; } v; v.u = u << 16; return v.f;
}
__device__ __forceinline__ float bfhi(unsigned int u) {
    union { unsigned int u; float f; } v; v.u = u & 0xFFFF0000u; return v.f;
}

// ---------------- 1: prep_h + prep_w + zero sliced cursors ----------------
__global__ __launch_bounds__(256) void prep_all(const int* __restrict__ node_ids,
                                                const float* __restrict__ emb,
                                                unsigned short* __restrict__ h_bf,
                                                const float* __restrict__ W,
                                                unsigned short* __restrict__ Wt,
                                                int* __restrict__ gcur) {
    const int b = blockIdx.x;
    const int t = threadIdx.x;
    if (b < PREPH_BLKS) {
        int gid = b * 256 + t;
        int row = gid >> 5;
        int c = (gid & 31) << 2;
        int nid = node_ids[row];
        if (nid < 0) nid = 0; if (nid >= NN) nid = NN - 1;
        float4 v = *(const float4*)(emb + (size_t)nid * HD + c);
        ushort4 o;
        o.x = f2bf(v.x); o.y = f2bf(v.y); o.z = f2bf(v.z); o.w = f2bf(v.w);
        *(ushort4*)(h_bf + (size_t)row * HD + c) = o;
    } else if (b < PREPH_BLKS + PREPW_BLKS) {
        int gid = (b - PREPH_BLKS) * 256 + t;
        int r = gid >> 14;
        int idx = gid & 16383;
        int k = idx >> 7;
        int o = idx & 127;
        Wt[(size_t)r * 16384 + (size_t)o * 128 + k] = f2bf(W[gid]);
    } else {
        for (int i = t; i < NCB * NSL; i += 256) gcur[i] = 0;
    }
}

// ---------------- 2: sliced global-atomic scatter -------------------------
// 16-way cursor privatization: contention per address 1024 -> 64.
__global__ __launch_bounds__(256) void scat(const int* __restrict__ src,
                                            const int* __restrict__ dst,
                                            const int* __restrict__ rel,
                                            const float* __restrict__ norm,
                                            int* __restrict__ gcur,
                                            uint2* __restrict__ recs) {
    int e = blockIdx.x * 256 + threadIdx.x;
    if (e >= NE) return;
    int slice = blockIdx.x & (NSL - 1);
    int d = dst[e];
    int bin = ((unsigned)d) >> 5;
    int p = atomicAdd(&gcur[bin * NSL + slice], 1);
    if (p < SCAP) {
        unsigned x = (unsigned)src[e] | ((unsigned)rel[e] << 16)
                   | ((unsigned)(d & 31) << 20);
        recs[(size_t)bin * SLOT + slice * SCAP + p] =
            make_uint2(x, __float_as_uint(norm[e]));
    }
}

// ---------------- 3: fused sort + RMW aggregate + MFMA (dbuf, 1 bar/rel) --
// out[d] = sum_r W[r]^T m[d,r],  m[d,r] = sum_{e:dst=d,rel=r} norm_e h[src_e]
// Bucket key = rel*4 + (sub&3): wave w owns rows sub%4==w -> plain
// ds_read/ds_write RMW (in-order DS pipe per wave), NO atomics.
// mF double-buffered: per rel {zero own rows of buf p; RMW-agg; barrier;
// MFMA reads buf p} -- MFMA(r) overlaps agg(r+1) on buf p^1.  Zero-own-rows
// at agg head is safe: barrier(r-1) drained all waves' MFMA(r-2) reads.
__global__ __launch_bounds__(256, 3) void seg_mm(const int* __restrict__ gcur,
                                                 const uint2* __restrict__ recs,
                                                 const unsigned int* __restrict__ hb,
                                                 const unsigned short* __restrict__ Wt,
                                                 float* __restrict__ out) {
    __shared__ unsigned pkS[SLOT];                   // 8 KB: src | sub<<16
    __shared__ float    normS[SLOT];                 // 8 KB
    __shared__ __align__(16) float mF[2 * 32 * 128]; // 32 KB dbuf (raw stage)
    __shared__ int h64[64], sbx[65], cur[64], c16[NSL], soff[NSL];
    const int t = threadIdx.x;
    const int bin = blockIdx.x;
    const uint2* rg = recs + (size_t)bin * SLOT;
    uint2* raw = (uint2*)mF;                         // staging in mF[0] half

    if (t < 64) h64[t] = 0;
    if (t < NSL) {
        int c = gcur[bin * NSL + t];
        c16[t] = c > SCAP ? SCAP : c;
    }
    __syncthreads();
    if (t == 0) {
        int run = 0;
        #pragma unroll
        for (int s = 0; s < NSL; ++s) { soff[s] = run; run += c16[s]; }
        sbx[64] = run;                               // stash total
    }
    __syncthreads();
    const int n = sbx[64];
    // compact slices + histogram
    #pragma unroll
    for (int s = 0; s < NSL; ++s) {
        if (t < c16[s]) {
            uint2 rc = rg[s * SCAP + t];
            raw[soff[s] + t] = rc;
            atomicAdd(&h64[((rc.x >> 16) & 15) * 4 + ((rc.x >> 20) & 3)], 1);
        }
    }
    __syncthreads();
    if (t == 0) {
        int run = 0;
        #pragma unroll
        for (int s = 0; s < 64; ++s) { sbx[s] = run; run += h64[s]; }
        sbx[64] = run;
    }
    __syncthreads();
    if (t < 64) cur[t] = sbx[t];
    __syncthreads();
    for (int i = t; i < n; i += 256) {
        uint2 rc = raw[i];
        int key = ((rc.x >> 16) & 15) * 4 + ((rc.x >> 20) & 3);
        int p = atomicAdd(&cur[key], 1);             // native LDS int atomic
        pkS[p] = (rc.x & 0xFFFFu) | (((rc.x >> 20) & 31u) << 16);
        normS[p] = __uint_as_float(rc.y);
    }
    __syncthreads();                                 // raw dead after this

    const int lane = t & 63;
    const int w = t >> 6;
    const int l15 = lane & 15, lhi = lane >> 4;
    const int colBase = w * 32;                      // wave's 32 output cols
    const int lane2 = 2 * lane;

    f32x4 acc[2][2];
    #pragma unroll
    for (int i = 0; i < 2; ++i)
        #pragma unroll
        for (int j = 0; j < 2; ++j)
            acc[i][j] = (f32x4){0.f, 0.f, 0.f, 0.f};

    for (int r = 0; r < NR; ++r) {
        float* mB = mF + (r & 1) * 4096;
        // ---- zero own rows (sub%4==w), 4 x ds_write_b128 ----
        #pragma unroll
        for (int j = 0; j < 4; ++j) {
            int flat = j * 256 + lane * 4;           // 0..1023
            int ri = flat >> 7;                      // own-row idx 0..7
            int c = flat & 127;
            *(f32x4*)&mB[((4 * ri + w) << 7) + c] = (f32x4){0.f, 0.f, 0.f, 0.f};
        }
        const int s = sbx[r * 4 + w], e = sbx[r * 4 + w + 1];
        // ---- branchless 8-deep gather + exclusive-row RMW accumulate ----
        for (int i0 = s; i0 < e; i0 += 8) {
            unsigned u8[8]; float nm[8]; int sb8[8];
            #pragma unroll
            for (int k = 0; k < 8; ++k) {
                int idx = i0 + k;
                int ci = idx < e ? idx : s;          // clamp: owned row, nm=0
                unsigned pk = pkS[ci];
                nm[k] = idx < e ? normS[ci] : 0.f;
                sb8[k] = (int)((pk >> 16) & 31u);
                u8[k] = hb[(size_t)(pk & 0xFFFFu) * 64u + (unsigned)lane];
            }
            #pragma unroll
            for (int k = 0; k < 8; ++k) {
                int woff = (sb8[k] << 7) + (lane2 ^ ((sb8[k] & 7) << 3));
                float2* mp = (float2*)&mB[woff];
                float2 v = *mp;                      // in-order DS: RAW safe
                v.x += bflo(u8[k]) * nm[k];
                v.y += bfhi(u8[k]) * nm[k];
                *mp = v;
            }
        }
        __syncthreads();                             // ONE barrier per rel

        // ---- MFMA: acc += m[32x128] @ W_r[128x128] (wave's 32 cols) ----
        const unsigned short* wp = Wt + ((size_t)r << 14);
        #pragma unroll
        for (int kt = 0; kt < 4; ++kt) {
            const int c0 = kt * 32 + lhi * 8;        // col/word base (x8)
            bf16x8 aF[2], bF[2];
            #pragma unroll
            for (int ms = 0; ms < 2; ++ms) {
                int row = ms * 16 + l15;
                const float* mp = &mB[(row << 7) + (c0 ^ ((row & 7) << 3))];
                f32x4 f0 = *(const f32x4*)mp;
                f32x4 f1 = *(const f32x4*)(mp + 4);
                u32x4 rv;
                #pragma unroll
                for (int j = 0; j < 2; ++j) {
                    union { __hip_bfloat162 h2; unsigned u; } cv;
                    cv.h2 = __float22bfloat162_rn(make_float2(f0[2 * j], f0[2 * j + 1]));
                    rv[j] = cv.u;
                }
                #pragma unroll
                for (int j = 0; j < 2; ++j) {
                    union { __hip_bfloat162 h2; unsigned u; } cv;
                    cv.h2 = __float22bfloat162_rn(make_float2(f1[2 * j], f1[2 * j + 1]));
                    rv[2 + j] = cv.u;
                }
                aF[ms] = __builtin_bit_cast(bf16x8, rv);
            }
            #pragma unroll
            for (int nt = 0; nt < 2; ++nt) {
                u16x8 rawB = *(const u16x8*)(wp + (size_t)(colBase + nt * 16 + l15) * 128 + c0);
                bF[nt] = __builtin_bit_cast(bf16x8, rawB);
            }
            #pragma unroll
            for (int ms = 0; ms < 2; ++ms)
                #pragma unroll
                for (int nt = 0; nt < 2; ++nt)
                    acc[ms][nt] = __builtin_amdgcn_mfma_f32_16x16x32_bf16(
                        aF[ms], bF[nt], acc[ms][nt], 0, 0, 0);
        }
        // no trailing barrier: next rel's zero+agg targets the other buffer;
        // next barrier (with lgkmcnt(0)) protects this buffer's reuse.
    }

    // ---- epilogue: C frag row = lhi*4+reg, col = l15 ----
    const int dbase = bin * 32;
    #pragma unroll
    for (int ms = 0; ms < 2; ++ms) {
        #pragma unroll
        for (int reg = 0; reg < 4; ++reg) {
            int d = dbase + ms * 16 + lhi * 4 + reg;
            if (d < NN) {
                #pragma unroll
                for (int nt = 0; nt < 2; ++nt)
                    out[(size_t)d * 128 + colBase + nt * 16 + l15] = acc[ms][nt][reg];
            }
        }
    }
}

// ---------------- launch ---------------------------------------------------

extern "C" void kernel_launch(void* const* d_in, const int* in_sizes, int n_in,
                              void* d_out, int out_size, void* d_ws, size_t ws_size,
                              hipStream_t stream) {
    const int* node_ids = (const int*)d_in[0];
    const int* src      = (const int*)d_in[1];
    const int* dst      = (const int*)d_in[2];
    const int* rel      = (const int*)d_in[3];
    const float* norm   = (const float*)d_in[4];
    const float* emb    = (const float*)d_in[5];
    const float* W      = (const float*)d_in[6];
    float* out = (float*)d_out;

    char* ws = (char*)d_ws;
    unsigned short* h_bf = (unsigned short*)(ws);              // 12,800,000 B
    unsigned short* Wt   = (unsigned short*)(ws + 12800000);   //    524,288 B
    int* gcur            = (int*)(ws + 13324288);              //    100,032 B (NCB*16)
    uint2* recs          = (uint2*)(ws + 13424384);            // 25,608,192 B
    // total ~39.0 MB

    prep_all<<<PREPH_BLKS + PREPW_BLKS + 1, 256, 0, stream>>>(
        node_ids, emb, h_bf, W, Wt, gcur);
    scat<<<SCAT_BLKS, 256, 0, stream>>>(src, dst, rel, norm, gcur, recs);
    seg_mm<<<NCB, 256, 0, stream>>>(gcur, recs,
                                    (const unsigned int*)h_bf, Wt, out);
}